// Round 1
// baseline (1292.459 us; speedup 1.0000x reference)
//
#include <hip/hip_runtime.h>
#include <math.h>

#define HEADS 4
#define HC 512          // HEADS * OUT_CH
#define CIN 128
#define COUT 128
#define NEG_SLOPE 0.2f

// ---- float <-> ordered-uint encoding for atomic max on floats ----
__device__ __forceinline__ unsigned enc_f(float f){
  unsigned u = __float_as_uint(f);
  return (u & 0x80000000u) ? ~u : (u | 0x80000000u);
}
__device__ __forceinline__ float dec_f(unsigned k){
  unsigned u = (k & 0x80000000u) ? (k & 0x7fffffffu) : ~k;
  return __uint_as_float(u);
}
#define ENC_NEGINF 0x007FFFFFu   // enc(-inf)

// ---- init m=-inf, s=0, hist=0 ----
__global__ void k_init(unsigned* __restrict__ m, float* __restrict__ s,
                       int* __restrict__ hist, int n){
  int i = blockIdx.x*blockDim.x + threadIdx.x;
  if (i < 4*n){ m[i] = ENC_NEGINF; s[i] = 0.f; }
  if (i < n) hist[i] = 0;
}

// ---- GEMM1: h = x @ lin_w   [n,128]@[128,512] ----
// 64-thread block, 8 rows x 512 cols per block; per-thread 8x8 tile.
__global__ __launch_bounds__(64) void k_lin(const float* __restrict__ x,
                                            const float* __restrict__ w,
                                            float* __restrict__ h, int n){
  __shared__ float xs[8*CIN];
  int row0 = blockIdx.x*8;
  int tid  = threadIdx.x;
  int rows = n - row0; if (rows > 8) rows = 8;
  const float4* x4 = (const float4*)(x + (size_t)row0*CIN);
  float4* xs4 = (float4*)xs;
  #pragma unroll
  for (int i=0;i<4;++i){
    int f = i*64 + tid;            // 0..255, row = f>>5
    float4 v = (f>>5) < rows ? x4[f] : make_float4(0,0,0,0);
    xs4[f] = v;
  }
  __syncthreads();
  float acc[8][8];
  #pragma unroll
  for (int r=0;r<8;++r)
    #pragma unroll
    for (int c=0;c<8;++c) acc[r][c] = 0.f;
  int c0 = tid*8;
  for (int k=0;k<CIN;k+=4){
    float4 xv[8];
    #pragma unroll
    for (int r=0;r<8;++r) xv[r] = *(const float4*)&xs[r*CIN+k];
    #pragma unroll
    for (int kk=0;kk<4;++kk){
      float4 w0 = *(const float4*)&w[(size_t)(k+kk)*HC + c0];
      float4 w1 = *(const float4*)&w[(size_t)(k+kk)*HC + c0 + 4];
      float wv[8] = {w0.x,w0.y,w0.z,w0.w,w1.x,w1.y,w1.z,w1.w};
      #pragma unroll
      for (int r=0;r<8;++r){
        float a = ((const float*)&xv[r])[kk];
        #pragma unroll
        for (int c=0;c<8;++c) acc[r][c] = fmaf(a, wv[c], acc[r][c]);
      }
    }
  }
  #pragma unroll
  for (int r=0;r<8;++r){
    if (r >= rows) break;
    float* hp = h + (size_t)(row0+r)*HC + c0;
    *(float4*)hp     = make_float4(acc[r][0],acc[r][1],acc[r][2],acc[r][3]);
    *(float4*)(hp+4) = make_float4(acc[r][4],acc[r][5],acc[r][6],acc[r][7]);
  }
}

// ---- attention dots: a_src[n,h] = <h[n,h,:], att_src[h,:]> ----
__global__ void k_attdot(const float* __restrict__ h,
                         const float* __restrict__ as_w,
                         const float* __restrict__ ad_w,
                         float* __restrict__ asrc, float* __restrict__ adst, int n){
  int node = blockIdx.x;
  int head = threadIdx.x >> 6, lane = threadIdx.x & 63;
  const float* hr = h + (size_t)node*HC + head*COUT;
  float v0 = hr[lane], v1 = hr[lane+64];
  float ps = v0*as_w[head*COUT+lane] + v1*as_w[head*COUT+lane+64];
  float pd = v0*ad_w[head*COUT+lane] + v1*ad_w[head*COUT+lane+64];
  #pragma unroll
  for (int off=32; off; off>>=1){ ps += __shfl_down(ps,off); pd += __shfl_down(pd,off); }
  if (lane==0){ asrc[node*4+head]=ps; adst[node*4+head]=pd; }
}

// ---- degree histogram by dst ----
__global__ void k_hist(const int* __restrict__ ei, int* __restrict__ hist, int E, int ET){
  int e = blockIdx.x*blockDim.x + threadIdx.x;
  if (e >= ET) return;
  int d = e < E ? ei[E+e] : e-E;
  atomicAdd(&hist[d], 1);
}

// ---- 3-phase exclusive scan (tile = 4096) ----
#define STILE 4096
__global__ __launch_bounds__(1024) void k_scan1(const int* __restrict__ in,
                                                int* __restrict__ out,
                                                int* __restrict__ tsum, int n){
  __shared__ int ls[1024];
  int b = blockIdx.x, tid = threadIdx.x;
  int base = b*STILE + tid*4;
  int v[4];
  #pragma unroll
  for (int i=0;i<4;++i){ int idx=base+i; v[i] = idx<n ? in[idx] : 0; }
  int run = v[0]+v[1]+v[2]+v[3];
  ls[tid]=run; __syncthreads();
  for (int off=1; off<1024; off<<=1){
    int t = (tid>=off) ? ls[tid-off] : 0;
    __syncthreads();
    ls[tid]+=t; __syncthreads();
  }
  int excl = ls[tid]-run;
  int sv[4]; sv[0]=excl+v[0]; sv[1]=sv[0]+v[1]; sv[2]=sv[1]+v[2]; sv[3]=sv[2]+v[3];
  #pragma unroll
  for (int i=0;i<4;++i){ int idx=base+i; if (idx<n) out[idx]=sv[i]; }
  if (tid==1023) tsum[b]=ls[1023];
}
__global__ void k_scan2(int* __restrict__ tsum, int T){
  if (threadIdx.x==0 && blockIdx.x==0){
    int off=0;
    for (int t=0;t<T;++t){ int v=tsum[t]; tsum[t]=off; off+=v; }
  }
}
__global__ void k_scan3(const int* __restrict__ scn, const int* __restrict__ toff,
                        int* __restrict__ rowptr, int n){
  int i = blockIdx.x*blockDim.x + threadIdx.x;
  if (i<n) rowptr[i+1] = scn[i] + toff[i/STILE];
  if (i==0) rowptr[0] = 0;
}
__global__ void k_cursor(const int* __restrict__ rowptr, int* __restrict__ cur, int n){
  int i = blockIdx.x*blockDim.x + threadIdx.x;
  if (i<n) cur[i] = rowptr[i];
}
__global__ void k_scatter(const int* __restrict__ ei, int* __restrict__ cur,
                          int* __restrict__ csr, int E, int ET){
  int e = blockIdx.x*blockDim.x + threadIdx.x;
  if (e >= ET) return;
  int d = e < E ? ei[E+e] : e-E;
  int pos = atomicAdd(&cur[d], 1);
  csr[pos] = e;
}

// ---- edge logits: leaky_relu(a_src[src]+a_dst[dst]); atomic segment max ----
__global__ void k_logits(const int* __restrict__ ei, const float* __restrict__ asrc,
                         const float* __restrict__ adst, float* __restrict__ eo,
                         unsigned* __restrict__ m, int E, int ET){
  int e = blockIdx.x*blockDim.x + threadIdx.x;
  if (e >= ET) return;
  int sN = e < E ? ei[e]   : e-E;
  int dN = e < E ? ei[E+e] : e-E;
  #pragma unroll
  for (int hh=0; hh<4; ++hh){
    float lg = asrc[sN*4+hh] + adst[dN*4+hh];
    lg = lg > 0.f ? lg : NEG_SLOPE*lg;
    eo[(size_t)e*4+hh] = lg;
    atomicMax(&m[dN*4+hh], enc_f(lg));
  }
}

// ---- exp(e - m[dst]); atomic segment sum ----
__global__ void k_expsum(const int* __restrict__ ei, float* __restrict__ eo,
                         const unsigned* __restrict__ m, float* __restrict__ s,
                         int E, int ET){
  int e = blockIdx.x*blockDim.x + threadIdx.x;
  if (e >= ET) return;
  int dN = e < E ? ei[E+e] : e-E;
  #pragma unroll
  for (int hh=0; hh<4; ++hh){
    float ex = expf(eo[(size_t)e*4+hh] - dec_f(m[dN*4+hh]));
    eo[(size_t)e*4+hh] = ex;
    atomicAdd(&s[dN*4+hh], ex);
  }
}

// ---- CSR aggregation: agg[d,:] = sum_e alpha*h[src,:] (no atomics) ----
__global__ __launch_bounds__(512) void k_agg(const int* __restrict__ ei,
                                             const int* __restrict__ rowptr,
                                             const int* __restrict__ csr,
                                             const float* __restrict__ eo,
                                             const float* __restrict__ ssum,
                                             const float* __restrict__ h,
                                             float* __restrict__ agg, int E, int n){
  int d = blockIdx.x, tid = threadIdx.x, head = tid>>7;
  int beg = rowptr[d], end = rowptr[d+1];
  float sinv = 1.f/(ssum[d*4+head] + 1e-16f);
  float acc = 0.f;
  for (int i=beg; i<end; ++i){
    int e  = csr[i];
    int sN = e < E ? ei[e] : e-E;
    float al = eo[(size_t)e*4+head];
    acc = fmaf(h[(size_t)sN*HC + tid], al, acc);
  }
  agg[(size_t)d*HC + tid] = acc*sinv;
}

// ---- epilogue: relu(agg+bias) @ proj_w + proj_b + x -> LayerNorm -> y ----
// 64-thread block, 8 rows; thread (tr=tid/16 -> 2 rows, tc=tid%16 -> 8 cols).
#define EPAD 516
__global__ __launch_bounds__(64) void k_epi(const float* __restrict__ agg,
                                            const float* __restrict__ gb,
                                            const float* __restrict__ pw,
                                            const float* __restrict__ pb,
                                            const float* __restrict__ x,
                                            const float* __restrict__ lng,
                                            const float* __restrict__ lnb,
                                            float* __restrict__ y, int n){
  __shared__ float sr[8*EPAD];
  int row0 = blockIdx.x*8, tid = threadIdx.x;
  int rows = n - row0; if (rows > 8) rows = 8;
  const float4* a4  = (const float4*)(agg + (size_t)row0*HC);
  const float4* gb4 = (const float4*)gb;
  #pragma unroll
  for (int i=0;i<16;++i){
    int f = i*64 + tid;            // 0..1023, row = f>>7
    int r = f>>7, kq = f & 127;
    float4 v = (r < rows) ? a4[f] : make_float4(0,0,0,0);
    float4 g = gb4[kq];
    v.x = fmaxf(v.x+g.x, 0.f); v.y = fmaxf(v.y+g.y, 0.f);
    v.z = fmaxf(v.z+g.z, 0.f); v.w = fmaxf(v.w+g.w, 0.f);
    *(float4*)&sr[r*EPAD + kq*4] = v;
  }
  __syncthreads();
  int tr = tid>>4, tc = tid&15;
  int r0 = tr*2, c0 = tc*8;
  float acc[2][8];
  #pragma unroll
  for (int rr=0;rr<2;++rr)
    #pragma unroll
    for (int c=0;c<8;++c) acc[rr][c]=0.f;
  for (int k=0;k<HC;k+=4){
    float4 a0 = *(const float4*)&sr[r0*EPAD + k];
    float4 a1 = *(const float4*)&sr[(r0+1)*EPAD + k];
    #pragma unroll
    for (int kk=0;kk<4;++kk){
      float4 w0 = *(const float4*)&pw[(size_t)(k+kk)*COUT + c0];
      float4 w1 = *(const float4*)&pw[(size_t)(k+kk)*COUT + c0 + 4];
      float wv[8] = {w0.x,w0.y,w0.z,w0.w,w1.x,w1.y,w1.z,w1.w};
      float av0 = ((const float*)&a0)[kk];
      float av1 = ((const float*)&a1)[kk];
      #pragma unroll
      for (int c=0;c<8;++c){
        acc[0][c] = fmaf(av0, wv[c], acc[0][c]);
        acc[1][c] = fmaf(av1, wv[c], acc[1][c]);
      }
    }
  }
  #pragma unroll
  for (int rr=0;rr<2;++rr){
    int row = row0 + r0 + rr;
    bool live = (r0+rr) < rows;
    float v[8]; float sum=0.f, sq=0.f;
    #pragma unroll
    for (int c=0;c<8;++c){
      float xv = live ? x[(size_t)row*COUT + c0 + c] : 0.f;
      float t = acc[rr][c] + pb[c0+c] + xv;
      v[c]=t; sum+=t; sq = fmaf(t,t,sq);
    }
    #pragma unroll
    for (int off=1; off<16; off<<=1){ sum += __shfl_xor(sum, off); sq += __shfl_xor(sq, off); }
    float mean = sum*(1.f/128.f);
    float var  = sq*(1.f/128.f) - mean*mean;
    float rstd = rsqrtf(var + 1e-5f);
    if (live){
      float o[8];
      #pragma unroll
      for (int c=0;c<8;++c) o[c] = (v[c]-mean)*rstd*lng[c0+c] + lnb[c0+c];
      float* yp = y + (size_t)row*COUT + c0;
      *(float4*)yp     = make_float4(o[0],o[1],o[2],o[3]);
      *(float4*)(yp+4) = make_float4(o[4],o[5],o[6],o[7]);
    }
  }
}

extern "C" void kernel_launch(void* const* d_in, const int* in_sizes, int n_in,
                              void* d_out, int out_size, void* d_ws, size_t ws_size,
                              hipStream_t stream){
  const float* x        = (const float*)d_in[0];
  const int*   ei       = (const int*)  d_in[1];
  const float* lin_w    = (const float*)d_in[2];
  const float* att_src  = (const float*)d_in[3];
  const float* att_dst  = (const float*)d_in[4];
  const float* gat_bias = (const float*)d_in[5];
  const float* proj_w   = (const float*)d_in[6];
  const float* proj_b   = (const float*)d_in[7];
  const float* ln_g     = (const float*)d_in[8];
  const float* ln_b     = (const float*)d_in[9];
  float* y = (float*)d_out;

  int n  = in_sizes[0]/CIN;
  int E  = in_sizes[1]/2;
  int ET = E + n;

  char* p = (char*)d_ws;
  auto alloc = [&](size_t bytes)->char*{
    char* r = p; p += (bytes + 255) & ~(size_t)255; return r;
  };
  float*    h      = (float*)   alloc((size_t)n*HC*4);
  float*    agg    = (float*)   alloc((size_t)n*HC*4);
  float*    asrc   = (float*)   alloc((size_t)n*4*4);
  float*    adst   = (float*)   alloc((size_t)n*4*4);
  unsigned* m      = (unsigned*)alloc((size_t)n*4*4);
  float*    ssum   = (float*)   alloc((size_t)n*4*4);
  float*    eo     = (float*)   alloc((size_t)ET*4*4);
  int*      hist   = (int*)     alloc((size_t)n*4);
  int*      scn    = (int*)     alloc((size_t)n*4);
  int*      rowptr = (int*)     alloc((size_t)(n+1)*4);
  int*      cursor = (int*)     alloc((size_t)n*4);
  int*      csr    = (int*)     alloc((size_t)ET*4);
  int T = (n + STILE-1)/STILE;
  int*      tsum   = (int*)     alloc((size_t)T*4);

  k_init   <<<(4*n+255)/256, 256, 0, stream>>>(m, ssum, hist, n);
  k_lin    <<<(n+7)/8, 64, 0, stream>>>(x, lin_w, h, n);
  k_attdot <<<n, 256, 0, stream>>>(h, att_src, att_dst, asrc, adst, n);
  k_hist   <<<(ET+255)/256, 256, 0, stream>>>(ei, hist, E, ET);
  k_scan1  <<<T, 1024, 0, stream>>>(hist, scn, tsum, n);
  k_scan2  <<<1, 64, 0, stream>>>(tsum, T);
  k_scan3  <<<(n+255)/256, 256, 0, stream>>>(scn, tsum, rowptr, n);
  k_cursor <<<(n+255)/256, 256, 0, stream>>>(rowptr, cursor, n);
  k_scatter<<<(ET+255)/256, 256, 0, stream>>>(ei, cursor, csr, E, ET);
  k_logits <<<(ET+255)/256, 256, 0, stream>>>(ei, asrc, adst, eo, m, E, ET);
  k_expsum <<<(ET+255)/256, 256, 0, stream>>>(ei, eo, m, ssum, E, ET);
  k_agg    <<<n, 512, 0, stream>>>(ei, rowptr, csr, eo, ssum, h, agg, E, n);
  k_epi    <<<(n+7)/8, 64, 0, stream>>>(agg, gat_bias, proj_w, proj_b, x, ln_g, ln_b, y, n);
}

// Round 2
// 826.803 us; speedup vs baseline: 1.5632x; 1.5632x over previous
//
#include <hip/hip_runtime.h>
#include <math.h>

#define HEADS 4
#define HC 512          // HEADS * OUT_CH
#define CIN 128
#define COUT 128
#define NEG_SLOPE 0.2f

// ---- float <-> ordered-uint encoding for atomic max on floats ----
__device__ __forceinline__ unsigned enc_f(float f){
  unsigned u = __float_as_uint(f);
  return (u & 0x80000000u) ? ~u : (u | 0x80000000u);
}
__device__ __forceinline__ float dec_f(unsigned k){
  unsigned u = (k & 0x80000000u) ? (k & 0x7fffffffu) : ~k;
  return __uint_as_float(u);
}
#define ENC_NEGINF 0x007FFFFFu   // enc(-inf)

__device__ __forceinline__ unsigned short f2bf(float f){
  unsigned u = __float_as_uint(f);
  unsigned r = u + 0x7fffu + ((u >> 16) & 1u);   // RNE
  return (unsigned short)(r >> 16);
}

// ---- init m=-inf, s=0, hist=0 ----
__global__ void k_init(unsigned* __restrict__ m, float* __restrict__ s,
                       int* __restrict__ hist, int n){
  int i = blockIdx.x*blockDim.x + threadIdx.x;
  if (i < 4*n){ m[i] = ENC_NEGINF; s[i] = 0.f; }
  if (i < n) hist[i] = 0;
}

// ---- GEMM1 fused: h2 = bf16(x @ lin_w); asrc/adst = <h, att_*> ----
// 64-thread block, 8 rows x 512 cols; per-thread 8x8 tile (cols tid*8..tid*8+7).
__global__ __launch_bounds__(64) void k_lin(const float* __restrict__ x,
                                            const float* __restrict__ w,
                                            const float* __restrict__ as_w,
                                            const float* __restrict__ ad_w,
                                            unsigned short* __restrict__ h2,
                                            float* __restrict__ asrc,
                                            float* __restrict__ adst, int n){
  __shared__ float xs[8*CIN];
  int row0 = blockIdx.x*8;
  int tid  = threadIdx.x;
  int rows = n - row0; if (rows > 8) rows = 8;
  const float4* x4 = (const float4*)(x + (size_t)row0*CIN);
  float4* xs4 = (float4*)xs;
  #pragma unroll
  for (int i=0;i<4;++i){
    int f = i*64 + tid;            // 0..255, row = f>>5
    float4 v = (f>>5) < rows ? x4[f] : make_float4(0,0,0,0);
    xs4[f] = v;
  }
  __syncthreads();
  float acc[8][8];
  #pragma unroll
  for (int r=0;r<8;++r)
    #pragma unroll
    for (int c=0;c<8;++c) acc[r][c] = 0.f;
  int c0 = tid*8;
  for (int k=0;k<CIN;k+=4){
    float4 xv[8];
    #pragma unroll
    for (int r=0;r<8;++r) xv[r] = *(const float4*)&xs[r*CIN+k];
    #pragma unroll
    for (int kk=0;kk<4;++kk){
      float4 w0 = *(const float4*)&w[(size_t)(k+kk)*HC + c0];
      float4 w1 = *(const float4*)&w[(size_t)(k+kk)*HC + c0 + 4];
      float wv[8] = {w0.x,w0.y,w0.z,w0.w,w1.x,w1.y,w1.z,w1.w};
      #pragma unroll
      for (int r=0;r<8;++r){
        float a = ((const float*)&xv[r])[kk];
        #pragma unroll
        for (int c=0;c<8;++c) acc[r][c] = fmaf(a, wv[c], acc[r][c]);
      }
    }
  }
  // attention dot weights for this thread's 8 columns
  int head = tid >> 4;            // c0/128
  int cc   = (tid & 15) * 8;      // col within head
  float asv[8], adv[8];
  #pragma unroll
  for (int c=0;c<8;++c){ asv[c] = as_w[head*COUT + cc + c]; adv[c] = ad_w[head*COUT + cc + c]; }
  #pragma unroll
  for (int r=0;r<8;++r){
    if (r >= rows) break;
    // store bf16 row chunk (16B per thread)
    unsigned short vs[8];
    #pragma unroll
    for (int c=0;c<8;++c) vs[c] = f2bf(acc[r][c]);
    *(uint4*)&h2[(size_t)(row0+r)*HC + c0] = *(uint4*)vs;
    // attention partial dots, reduce across the 16 lanes of this head
    float ps = 0.f, pd = 0.f;
    #pragma unroll
    for (int c=0;c<8;++c){ ps = fmaf(acc[r][c], asv[c], ps); pd = fmaf(acc[r][c], adv[c], pd); }
    #pragma unroll
    for (int off=1; off<16; off<<=1){ ps += __shfl_xor(ps, off); pd += __shfl_xor(pd, off); }
    if ((tid & 15) == 0){
      asrc[(size_t)(row0+r)*4 + head] = ps;
      adst[(size_t)(row0+r)*4 + head] = pd;
    }
  }
}

// ---- edge logits: leaky_relu(a_src[src]+a_dst[dst]); atomic max; dst histogram ----
__global__ void k_logits(const int* __restrict__ ei, const float* __restrict__ asrc,
                         const float* __restrict__ adst, float* __restrict__ eo,
                         unsigned* __restrict__ m, int* __restrict__ hist,
                         int E, int ET){
  int e = blockIdx.x*blockDim.x + threadIdx.x;
  if (e >= ET) return;
  int sN = e < E ? ei[e]   : e-E;
  int dN = e < E ? ei[E+e] : e-E;
  atomicAdd(&hist[dN], 1);
  #pragma unroll
  for (int hh=0; hh<4; ++hh){
    float lg = asrc[sN*4+hh] + adst[dN*4+hh];
    lg = lg > 0.f ? lg : NEG_SLOPE*lg;
    eo[(size_t)e*4+hh] = lg;
    atomicMax(&m[dN*4+hh], enc_f(lg));
  }
}

// ---- 3-phase exclusive scan (tile = 4096) ----
#define STILE 4096
__global__ __launch_bounds__(1024) void k_scan1(const int* __restrict__ in,
                                                int* __restrict__ out,
                                                int* __restrict__ tsum, int n){
  __shared__ int ls[1024];
  int b = blockIdx.x, tid = threadIdx.x;
  int base = b*STILE + tid*4;
  int v[4];
  #pragma unroll
  for (int i=0;i<4;++i){ int idx=base+i; v[i] = idx<n ? in[idx] : 0; }
  int run = v[0]+v[1]+v[2]+v[3];
  ls[tid]=run; __syncthreads();
  for (int off=1; off<1024; off<<=1){
    int t = (tid>=off) ? ls[tid-off] : 0;
    __syncthreads();
    ls[tid]+=t; __syncthreads();
  }
  int excl = ls[tid]-run;
  int sv[4]; sv[0]=excl+v[0]; sv[1]=sv[0]+v[1]; sv[2]=sv[1]+v[2]; sv[3]=sv[2]+v[3];
  #pragma unroll
  for (int i=0;i<4;++i){ int idx=base+i; if (idx<n) out[idx]=sv[i]; }
  if (tid==1023) tsum[b]=ls[1023];
}
__global__ void k_scan2(int* __restrict__ tsum, int T){
  if (threadIdx.x==0 && blockIdx.x==0){
    int off=0;
    for (int t=0;t<T;++t){ int v=tsum[t]; tsum[t]=off; off+=v; }
  }
}
__global__ void k_scan3(const int* __restrict__ scn, const int* __restrict__ toff,
                        int* __restrict__ rowptr, int* __restrict__ cur, int n){
  int i = blockIdx.x*blockDim.x + threadIdx.x;
  if (i<n){
    int v = scn[i] + toff[i/STILE];
    rowptr[i+1] = v;
  }
  if (i<n){ cur[i] = (i==0) ? 0 : scn[i-1] + toff[(i-1)/STILE]; }
  if (i==0) rowptr[0] = 0;
}

// ---- exp(e - m[dst]); atomic segment sum ----
__global__ void k_expsum(const int* __restrict__ ei, float* __restrict__ eo,
                         const unsigned* __restrict__ m, float* __restrict__ s,
                         int E, int ET){
  int e = blockIdx.x*blockDim.x + threadIdx.x;
  if (e >= ET) return;
  int dN = e < E ? ei[E+e] : e-E;
  #pragma unroll
  for (int hh=0; hh<4; ++hh){
    float ex = expf(eo[(size_t)e*4+hh] - dec_f(m[dN*4+hh]));
    eo[(size_t)e*4+hh] = ex;
    atomicAdd(&s[dN*4+hh], ex);
  }
}

// ---- scatter: build pre-resolved CSR payload (src id + normalized alpha4) ----
__global__ void k_scatter(const int* __restrict__ ei, int* __restrict__ cur,
                          const float* __restrict__ eo, const float* __restrict__ ssum,
                          int* __restrict__ srcs, float* __restrict__ aw,
                          int E, int ET){
  int e = blockIdx.x*blockDim.x + threadIdx.x;
  if (e >= ET) return;
  int sN = e < E ? ei[e]   : e-E;
  int dN = e < E ? ei[E+e] : e-E;
  int pos = atomicAdd(&cur[dN], 1);
  srcs[pos] = sN;
  float4 ex = *(const float4*)&eo[(size_t)e*4];
  float4 sv = *(const float4*)&ssum[(size_t)dN*4];
  float4 a = make_float4(ex.x/(sv.x+1e-16f), ex.y/(sv.y+1e-16f),
                         ex.z/(sv.z+1e-16f), ex.w/(sv.w+1e-16f));
  *(float4*)&aw[(size_t)pos*4] = a;
}

// ---- CSR aggregation: agg[d,:] = sum_i alpha[i]*h2[srcs[i],:] ----
// 256 threads; thread covers cols {2*tid, 2*tid+1}; head = tid>>6.
__global__ __launch_bounds__(256) void k_agg(const int* __restrict__ rowptr,
                                             const int* __restrict__ srcs,
                                             const float* __restrict__ aw,
                                             const unsigned* __restrict__ h2v,
                                             float* __restrict__ agg, int n){
  int d = blockIdx.x, tid = threadIdx.x, head = tid>>6;
  int beg = rowptr[d], end = rowptr[d+1];
  float ax = 0.f, ay = 0.f;
  #pragma unroll 4
  for (int i=beg; i<end; ++i){
    int s   = srcs[i];
    float a = aw[(size_t)i*4 + head];
    unsigned v = h2v[(size_t)s*256 + tid];
    float f0 = __uint_as_float(v << 16);
    float f1 = __uint_as_float(v & 0xffff0000u);
    ax = fmaf(f0, a, ax);
    ay = fmaf(f1, a, ay);
  }
  *(float2*)&agg[(size_t)d*HC + tid*2] = make_float2(ax, ay);
}

// ---- epilogue: relu(agg+bias) @ proj_w + proj_b + x -> LayerNorm -> y ----
#define EPAD 516
__global__ __launch_bounds__(64) void k_epi(const float* __restrict__ agg,
                                            const float* __restrict__ gb,
                                            const float* __restrict__ pw,
                                            const float* __restrict__ pb,
                                            const float* __restrict__ x,
                                            const float* __restrict__ lng,
                                            const float* __restrict__ lnb,
                                            float* __restrict__ y, int n){
  __shared__ float sr[8*EPAD];
  int row0 = blockIdx.x*8, tid = threadIdx.x;
  int rows = n - row0; if (rows > 8) rows = 8;
  const float4* a4  = (const float4*)(agg + (size_t)row0*HC);
  const float4* gb4 = (const float4*)gb;
  #pragma unroll
  for (int i=0;i<16;++i){
    int f = i*64 + tid;            // 0..1023, row = f>>7
    int r = f>>7, kq = f & 127;
    float4 v = (r < rows) ? a4[f] : make_float4(0,0,0,0);
    float4 g = gb4[kq];
    v.x = fmaxf(v.x+g.x, 0.f); v.y = fmaxf(v.y+g.y, 0.f);
    v.z = fmaxf(v.z+g.z, 0.f); v.w = fmaxf(v.w+g.w, 0.f);
    *(float4*)&sr[r*EPAD + kq*4] = v;
  }
  __syncthreads();
  int tr = tid>>4, tc = tid&15;
  int r0 = tr*2, c0 = tc*8;
  float acc[2][8];
  #pragma unroll
  for (int rr=0;rr<2;++rr)
    #pragma unroll
    for (int c=0;c<8;++c) acc[rr][c]=0.f;
  for (int k=0;k<HC;k+=4){
    float4 a0 = *(const float4*)&sr[r0*EPAD + k];
    float4 a1 = *(const float4*)&sr[(r0+1)*EPAD + k];
    #pragma unroll
    for (int kk=0;kk<4;++kk){
      float4 w0 = *(const float4*)&pw[(size_t)(k+kk)*COUT + c0];
      float4 w1 = *(const float4*)&pw[(size_t)(k+kk)*COUT + c0 + 4];
      float wv[8] = {w0.x,w0.y,w0.z,w0.w,w1.x,w1.y,w1.z,w1.w};
      float av0 = ((const float*)&a0)[kk];
      float av1 = ((const float*)&a1)[kk];
      #pragma unroll
      for (int c=0;c<8;++c){
        acc[0][c] = fmaf(av0, wv[c], acc[0][c]);
        acc[1][c] = fmaf(av1, wv[c], acc[1][c]);
      }
    }
  }
  #pragma unroll
  for (int rr=0;rr<2;++rr){
    int row = row0 + r0 + rr;
    bool live = (r0+rr) < rows;
    float v[8]; float sum=0.f, sq=0.f;
    #pragma unroll
    for (int c=0;c<8;++c){
      float xv = live ? x[(size_t)row*COUT + c0 + c] : 0.f;
      float t = acc[rr][c] + pb[c0+c] + xv;
      v[c]=t; sum+=t; sq = fmaf(t,t,sq);
    }
    #pragma unroll
    for (int off=1; off<16; off<<=1){ sum += __shfl_xor(sum, off); sq += __shfl_xor(sq, off); }
    float mean = sum*(1.f/128.f);
    float var  = sq*(1.f/128.f) - mean*mean;
    float rstd = rsqrtf(var + 1e-5f);
    if (live){
      float o[8];
      #pragma unroll
      for (int c=0;c<8;++c) o[c] = (v[c]-mean)*rstd*lng[c0+c] + lnb[c0+c];
      float* yp = y + (size_t)row*COUT + c0;
      *(float4*)yp     = make_float4(o[0],o[1],o[2],o[3]);
      *(float4*)(yp+4) = make_float4(o[4],o[5],o[6],o[7]);
    }
  }
}

extern "C" void kernel_launch(void* const* d_in, const int* in_sizes, int n_in,
                              void* d_out, int out_size, void* d_ws, size_t ws_size,
                              hipStream_t stream){
  const float* x        = (const float*)d_in[0];
  const int*   ei       = (const int*)  d_in[1];
  const float* lin_w    = (const float*)d_in[2];
  const float* att_src  = (const float*)d_in[3];
  const float* att_dst  = (const float*)d_in[4];
  const float* gat_bias = (const float*)d_in[5];
  const float* proj_w   = (const float*)d_in[6];
  const float* proj_b   = (const float*)d_in[7];
  const float* ln_g     = (const float*)d_in[8];
  const float* ln_b     = (const float*)d_in[9];
  float* y = (float*)d_out;

  int n  = in_sizes[0]/CIN;
  int E  = in_sizes[1]/2;
  int ET = E + n;

  char* p = (char*)d_ws;
  auto alloc = [&](size_t bytes)->char*{
    char* r = p; p += (bytes + 255) & ~(size_t)255; return r;
  };
  unsigned short* h2 = (unsigned short*)alloc((size_t)n*HC*2);
  float*    agg    = (float*)   alloc((size_t)n*HC*4);
  float*    asrc   = (float*)   alloc((size_t)n*4*4);
  float*    adst   = (float*)   alloc((size_t)n*4*4);
  unsigned* m      = (unsigned*)alloc((size_t)n*4*4);
  float*    ssum   = (float*)   alloc((size_t)n*4*4);
  float*    eo     = (float*)   alloc((size_t)ET*4*4);
  int*      hist   = (int*)     alloc((size_t)n*4);
  int*      scn    = (int*)     alloc((size_t)n*4);
  int*      rowptr = (int*)     alloc((size_t)(n+1)*4);
  int*      cursor = (int*)     alloc((size_t)n*4);
  int*      srcs   = (int*)     alloc((size_t)ET*4);
  float*    aw     = (float*)   alloc((size_t)ET*4*4);
  int T = (n + STILE-1)/STILE;
  int*      tsum   = (int*)     alloc((size_t)T*4);

  k_init   <<<(4*n+255)/256, 256, 0, stream>>>(m, ssum, hist, n);
  k_lin    <<<(n+7)/8, 64, 0, stream>>>(x, lin_w, att_src, att_dst, h2, asrc, adst, n);
  k_logits <<<(ET+255)/256, 256, 0, stream>>>(ei, asrc, adst, eo, m, hist, E, ET);
  k_scan1  <<<T, 1024, 0, stream>>>(hist, scn, tsum, n);
  k_scan2  <<<1, 64, 0, stream>>>(tsum, T);
  k_scan3  <<<(n+255)/256, 256, 0, stream>>>(scn, tsum, rowptr, cursor, n);
  k_expsum <<<(ET+255)/256, 256, 0, stream>>>(ei, eo, m, ssum, E, ET);
  k_scatter<<<(ET+255)/256, 256, 0, stream>>>(ei, cursor, eo, ssum, srcs, aw, E, ET);
  k_agg    <<<n, 256, 0, stream>>>(rowptr, srcs, aw, (const unsigned*)h2, agg, n);
  k_epi    <<<(n+7)/8, 64, 0, stream>>>(agg, gat_bias, proj_w, proj_b, x, ln_g, ln_b, y, n);
}